// Round 3
// baseline (1348.052 us; speedup 1.0000x reference)
//
#include <hip/hip_runtime.h>
#include <hip/hip_bf16.h>
#include <stdint.h>

// Problem constants: B=2, S=1024 -> T=2048; D=1024; E=8; F=4096
#define DDIM 1024
#define EXP 8
#define FDIM 4096
#define BK 32
#define LDT 40   // LDS row stride (bf16 elems): 80B rows -> 16B-aligned, 2-way-max read conflicts

typedef __attribute__((ext_vector_type(8))) short bf16x8;
typedef __attribute__((ext_vector_type(8))) short short8v;
typedef __attribute__((ext_vector_type(4))) short short4v;
typedef __attribute__((ext_vector_type(4))) float f32x4;

__device__ __forceinline__ unsigned short f2bf(float f) {
    unsigned u = __float_as_uint(f);
    u += 0x7FFFu + ((u >> 16) & 1u);          // round-to-nearest-even
    return (unsigned short)(u >> 16);
}
__device__ __forceinline__ float bf2f(unsigned short h) {
    return __uint_as_float(((unsigned)h) << 16);
}

// ---------------------------------------------------------------------------
// Split x into bf16 hi/lo planes.
// ---------------------------------------------------------------------------
__global__ __launch_bounds__(256) void splitx_kernel(
    const float* __restrict__ x, unsigned short* __restrict__ Xh,
    unsigned short* __restrict__ Xl, int total4)
{
    int i = blockIdx.x * 256 + threadIdx.x;
    if (i >= total4) return;
    float4 v = ((const float4*)x)[i];
    float f[4] = {v.x, v.y, v.z, v.w};
    short4v h4, l4;
#pragma unroll
    for (int j = 0; j < 4; ++j) {
        unsigned short hh = f2bf(f[j]);
        h4[j] = (short)hh;
        l4[j] = (short)f2bf(f[j] - bf2f(hh));
    }
    ((short4v*)Xh)[i] = h4;
    ((short4v*)Xl)[i] = l4;
}

// ---------------------------------------------------------------------------
// Router: logits + alpha-entmax(1.5) bisection + threshold; also Gb2[t,:] =
// sum_e g[t,e]*b2[e,:]. One 256-thread block per token.
// ---------------------------------------------------------------------------
__global__ __launch_bounds__(256) void router_kernel(
    const float* __restrict__ x, const float* __restrict__ Wr,
    const float* __restrict__ br, const float* __restrict__ b2,
    float* __restrict__ gates, float* __restrict__ Gb2)
{
    const int t = blockIdx.x;
    const int tid = threadIdx.x;
    const float* xr = x + (size_t)t * DDIM;

    float acc[EXP];
#pragma unroll
    for (int e = 0; e < EXP; ++e) acc[e] = 0.f;
    for (int d = tid; d < DDIM; d += 256) {
        float xv = xr[d];
        const float* wr = Wr + (size_t)d * EXP;
#pragma unroll
        for (int e = 0; e < EXP; ++e) acc[e] += xv * wr[e];
    }
#pragma unroll
    for (int e = 0; e < EXP; ++e) {
        float v = acc[e];
#pragma unroll
        for (int off = 32; off > 0; off >>= 1) v += __shfl_down(v, off);
        acc[e] = v;
    }
    __shared__ float part[4][EXP];
    __shared__ float gsh[EXP];
    const int wave = tid >> 6, lane = tid & 63;
    if (lane == 0) {
#pragma unroll
        for (int e = 0; e < EXP; ++e) part[wave][e] = acc[e];
    }
    __syncthreads();

    if (tid == 0) {
        float Xs[EXP];
        float mx = -1e30f;
#pragma unroll
        for (int e = 0; e < EXP; ++e) {
            float lg = part[0][e] + part[1][e] + part[2][e] + part[3][e] + br[e];
            Xs[e] = 0.5f * lg;                          // *(alpha-1), TEMP=1
            mx = fmaxf(mx, Xs[e]);
        }
        float tau_lo = mx - 1.0f;
        const float tau_hi = mx - 0.35355339059327373f; // (1/8)^0.5
        float f_lo = -1.0f;
#pragma unroll
        for (int e = 0; e < EXP; ++e) {
            float u = fmaxf(Xs[e] - tau_lo, 0.f);
            f_lo += u * u;                              // inv_am1 = 2
        }
        float dm = tau_hi - tau_lo;
        float tau_m = tau_lo;
        for (int it = 0; it < 25; ++it) {
            dm *= 0.5f;
            tau_m = tau_lo + dm;
            float f_m = -1.0f;
#pragma unroll
            for (int e = 0; e < EXP; ++e) {
                float u = fmaxf(Xs[e] - tau_m, 0.f);
                f_m += u * u;
            }
            if (f_m * f_lo >= 0.f) tau_lo = tau_m;
        }
        float p[EXP], s = 0.f;
#pragma unroll
        for (int e = 0; e < EXP; ++e) {
            float u = fmaxf(Xs[e] - tau_m, 0.f);
            p[e] = u * u;
            s += p[e];
        }
        float inv = 1.f / s;
#pragma unroll
        for (int e = 0; e < EXP; ++e) {
            float g = p[e] * inv;
            g = (g > 1e-9f) ? g : 0.f;                  // activation threshold
            gates[(size_t)t * EXP + e] = g;
            gsh[e] = g;
        }
    }
    __syncthreads();

    // Gb2[t, d] = sum_e g[e]*b2[e][d]; 256 thr * float4 = 1024 = DDIM
    const int d = tid * 4;
    float4 s4 = {0.f, 0.f, 0.f, 0.f};
#pragma unroll
    for (int e = 0; e < EXP; ++e) {
        float g = gsh[e];
        float4 bb = *(const float4*)(b2 + (size_t)e * DDIM + d);
        s4.x += g * bb.x; s4.y += g * bb.y; s4.z += g * bb.z; s4.w += g * bb.w;
    }
    *(float4*)(Gb2 + (size_t)t * DDIM + d) = s4;
}

// ---------------------------------------------------------------------------
// Split-bf16 MFMA GEMM: C = A(fp32 via pre-split hi/lo bf16) @ W(fp32, split
// on the fly). 128x128 tile, BK=32, 4 waves (2x2), wave-tile 64x64 (4x4 frags
// of 16x16x32). Both operands staged k-contiguous-8 with the SAME assumed
// K-mapping -> result invariant to the true HW K-permutation (only the
// m89-verified A-row/B-col/C-D facts are load-bearing).
// EPI=1: H[e][m][f] = split( relu(C + b1[e][f]) * gate ), write hi/lo bf16.
// EPI=2: P[e][m][d] = C (fp32 partial, reduced later).
// Grid: (CT/128, N/128, EXP).
// ---------------------------------------------------------------------------
template<int EPI>
__global__ __launch_bounds__(256) void gemm_kernel(
    const unsigned short* __restrict__ Ah, const unsigned short* __restrict__ Al,
    int lda, const float* __restrict__ W, int K, int N,
    const float* __restrict__ bias, const float* __restrict__ gates,
    unsigned short* __restrict__ Oh, unsigned short* __restrict__ Ol,
    float* __restrict__ P, int CT, int t0)
{
    const int e  = blockIdx.z;
    const int m0 = blockIdx.x * 128;
    const int n0 = blockIdx.y * 128;
    const int tid = threadIdx.x;
    const int lane = tid & 63;
    const int wid = tid >> 6;
    const int wr = wid >> 1, wc = wid & 1;

    __shared__ unsigned short sAh[128 * LDT], sAl[128 * LDT];
    __shared__ unsigned short sBh[128 * LDT], sBl[128 * LDT];

    const float* Wg = W + (size_t)e * K * N;
    const long abase = (EPI == 1) ? (long)t0 : (long)e * CT;

    // A staging: row am (0..127), k-half ak (0/16); pure bf16 copies.
    const int am = tid >> 1;
    const int ak = (tid & 1) * 16;
    const unsigned short* Agh = Ah + (size_t)(abase + m0 + am) * lda + ak;
    const unsigned short* Agl = Al + (size_t)(abase + m0 + am) * lda + ak;

    // B staging: k-major lanes; 4x4 transpose + split into LDS.
    const int bk = (tid & 7) * 4;          // 0..28
    const int bn = ((tid >> 3) & 31) * 4;  // 0..124
    const float* Bg = Wg + (size_t)bk * N + n0 + bn;

    f32x4 acc[4][4];
#pragma unroll
    for (int mi = 0; mi < 4; ++mi)
#pragma unroll
        for (int ni = 0; ni < 4; ++ni) acc[mi][ni] = (f32x4){0.f, 0.f, 0.f, 0.f};

    const int lr = lane & 15, lg = lane >> 4;

    for (int kt = 0; kt < K; kt += BK) {
        // issue global loads before the barrier (overlap with prior compute)
        short8v a_h0 = *(const short8v*)(Agh + kt);
        short8v a_h1 = *(const short8v*)(Agh + kt + 8);
        short8v a_l0 = *(const short8v*)(Agl + kt);
        short8v a_l1 = *(const short8v*)(Agl + kt + 8);
        float4 bv[4];
#pragma unroll
        for (int i = 0; i < 4; ++i)
            bv[i] = *(const float4*)(Bg + (size_t)(kt + i) * N);

        __syncthreads();   // prior compute done; LDS reusable

        *(short8v*)&sAh[am * LDT + ak]     = a_h0;
        *(short8v*)&sAh[am * LDT + ak + 8] = a_h1;
        *(short8v*)&sAl[am * LDT + ak]     = a_l0;
        *(short8v*)&sAl[am * LDT + ak + 8] = a_l1;

#pragma unroll
        for (int j = 0; j < 4; ++j) {      // transpose 4x4 + split
            short4v h4, l4;
#pragma unroll
            for (int i = 0; i < 4; ++i) {
                float f = ((const float*)&bv[i])[j];
                unsigned short hh = f2bf(f);
                h4[i] = (short)hh;
                l4[i] = (short)f2bf(f - bf2f(hh));
            }
            *(short4v*)&sBh[(bn + j) * LDT + bk] = h4;
            *(short4v*)&sBl[(bn + j) * LDT + bk] = l4;
        }
        __syncthreads();

        bf16x8 afh[4], afl[4];
#pragma unroll
        for (int mi = 0; mi < 4; ++mi) {
            int row = wr * 64 + mi * 16 + lr;
            afh[mi] = *(const bf16x8*)&sAh[row * LDT + lg * 8];
            afl[mi] = *(const bf16x8*)&sAl[row * LDT + lg * 8];
        }
#pragma unroll
        for (int ni = 0; ni < 4; ++ni) {
            int col = wc * 64 + ni * 16 + lr;
            bf16x8 bfh = *(const bf16x8*)&sBh[col * LDT + lg * 8];
            bf16x8 bfl = *(const bf16x8*)&sBl[col * LDT + lg * 8];
#pragma unroll
            for (int mi = 0; mi < 4; ++mi) {
                acc[mi][ni] = __builtin_amdgcn_mfma_f32_16x16x32_bf16(afh[mi], bfh, acc[mi][ni], 0, 0, 0);
                acc[mi][ni] = __builtin_amdgcn_mfma_f32_16x16x32_bf16(afh[mi], bfl, acc[mi][ni], 0, 0, 0);
                acc[mi][ni] = __builtin_amdgcn_mfma_f32_16x16x32_bf16(afl[mi], bfh, acc[mi][ni], 0, 0, 0);
            }
        }
    }

    // Epilogue. C/D layout (m89-verified): col = lane&15, row = (lane>>4)*4+reg.
#pragma unroll
    for (int mi = 0; mi < 4; ++mi) {
#pragma unroll
        for (int ni = 0; ni < 4; ++ni) {
            const int col = n0 + wc * 64 + ni * 16 + lr;
#pragma unroll
            for (int r = 0; r < 4; ++r) {
                const int mrow = m0 + wr * 64 + mi * 16 + lg * 4 + r; // chunk-local row
                float v = acc[mi][ni][r];
                if (EPI == 1) {
                    float g = gates[(size_t)(t0 + mrow) * EXP + e];
                    v = fmaxf(v + bias[(size_t)e * FDIM + col], 0.f) * g;
                    unsigned short hh = f2bf(v);
                    size_t idx = ((size_t)e * CT + mrow) * FDIM + col;
                    Oh[idx] = hh;
                    Ol[idx] = f2bf(v - bf2f(hh));
                } else {
                    P[((size_t)e * CT + mrow) * DDIM + col] = v;
                }
            }
        }
    }
}

// ---------------------------------------------------------------------------
// out[t0+m, d] = sum_e P[e][m][d] + Gb2[t0+m][d]
// ---------------------------------------------------------------------------
__global__ __launch_bounds__(256) void reduce_kernel(
    const float* __restrict__ P, const float* __restrict__ Gb2,
    float* __restrict__ out, int t0, int CT)
{
    int i = blockIdx.x * 256 + threadIdx.x;        // float4 index within chunk
    int total4 = CT * DDIM / 4;
    if (i >= total4) return;
    size_t goff = (size_t)t0 * DDIM / 4 + i;
    float4 s = ((const float4*)Gb2)[goff];
#pragma unroll
    for (int e = 0; e < EXP; ++e) {
        float4 p = ((const float4*)P)[(size_t)e * CT * DDIM / 4 + i];
        s.x += p.x; s.y += p.y; s.z += p.z; s.w += p.w;
    }
    ((float4*)out)[goff] = s;
}

// ---------------------------------------------------------------------------
extern "C" void kernel_launch(void* const* d_in, const int* in_sizes, int n_in,
                              void* d_out, int out_size, void* d_ws, size_t ws_size,
                              hipStream_t stream)
{
    const float* x  = (const float*)d_in[0];
    const float* Wr = (const float*)d_in[1];
    const float* br = (const float*)d_in[2];
    const float* W1 = (const float*)d_in[3];
    const float* b1 = (const float*)d_in[4];
    const float* W2 = (const float*)d_in[5];
    const float* b2 = (const float*)d_in[6];
    float* out = (float*)d_out;

    const int T = in_sizes[0] / DDIM;   // 2048

    // ---- workspace carve (256B aligned) ----
    char* p = (char*)d_ws;
    size_t used = 0;
    auto carve = [&](size_t bytes) {
        char* r = p + used;
        used += (bytes + 255) & ~(size_t)255;
        return r;
    };
    float* gates = (float*)carve((size_t)T * EXP * 4);
    float* Gb2   = (float*)carve((size_t)T * DDIM * 4);
    unsigned short* Xh = (unsigned short*)carve((size_t)T * DDIM * 2);
    unsigned short* Xl = (unsigned short*)carve((size_t)T * DDIM * 2);

    // per-token bytes for chunked buffers: H hi/lo (E*F*2*2) + P (E*D*4)
    const size_t per_tok = (size_t)EXP * FDIM * 4 + (size_t)EXP * DDIM * 4; // 163840
    size_t avail = (ws_size > used) ? (ws_size - used) : 0;
    int CT = 128;
    for (int c = 2048; c >= 128; c >>= 1) {
        if ((size_t)c * per_tok + 1024 <= avail) { CT = c; break; }
    }
    if (CT > T) CT = T;
    unsigned short* Hh = (unsigned short*)carve((size_t)EXP * CT * FDIM * 2);
    unsigned short* Hl = (unsigned short*)carve((size_t)EXP * CT * FDIM * 2);
    float*          Pp = (float*)carve((size_t)EXP * CT * DDIM * 4);

    // ---- launches ----
    const int total4x = T * DDIM / 4;
    splitx_kernel<<<dim3((total4x + 255) / 256), dim3(256), 0, stream>>>(x, Xh, Xl, total4x);
    router_kernel<<<dim3(T), dim3(256), 0, stream>>>(x, Wr, br, b2, gates, Gb2);

    for (int t0 = 0; t0 < T; t0 += CT) {
        // GEMM1: A = X splits [T][1024], B = W1[e] [1024][4096] -> H splits
        dim3 g1(CT / 128, FDIM / 128, EXP);
        gemm_kernel<1><<<g1, dim3(256), 0, stream>>>(
            Xh, Xl, DDIM, W1, DDIM, FDIM, b1, gates, Hh, Hl, (float*)nullptr, CT, t0);
        // GEMM2: A = H splits [E*CT][4096], B = W2[e] [4096][1024] -> P
        dim3 g2(CT / 128, DDIM / 128, EXP);
        gemm_kernel<2><<<g2, dim3(256), 0, stream>>>(
            Hh, Hl, FDIM, W2, FDIM, DDIM, (const float*)nullptr, (const float*)nullptr,
            (unsigned short*)nullptr, (unsigned short*)nullptr, Pp, CT, t0);
        // reduce partials + gated bias
        reduce_kernel<<<dim3((CT * DDIM / 4 + 255) / 256), dim3(256), 0, stream>>>(
            Pp, Gb2, out, t0, CT);
    }
}